// Round 10
// baseline (373.189 us; speedup 1.0000x reference)
//
#include <hip/hip_runtime.h>
#include <math.h>

#define DIMC 1024
#define BB   8
#define LL   2048
#define ACTC 256
#define HIDC 256
#define EPSV 1e-6f
#define MROWS (BB * LL)   // 16384
#define NCHUNK 128        // R10: 32->128. scan_a chain 64->16 dependent loads, grid 256->1024
#define LC     16         // LL / NCHUNK

typedef __bf16 bf16x8 __attribute__((ext_vector_type(8)));
typedef float  f32x4  __attribute__((ext_vector_type(4)));

__device__ __forceinline__ unsigned short f2bf(float f) {
    union { float f; unsigned int u; } v; v.f = f;
    unsigned int u = v.u + 0x7fffu + ((v.u >> 16) & 1u);
    return (unsigned short)(u >> 16);
}
__device__ __forceinline__ float bf2f(unsigned short s) {
    union { float f; unsigned int u; } v; v.u = ((unsigned int)s) << 16;
    return v.f;
}
// inf-safe fast sigmoid/tanh on native v_exp_f32
__device__ __forceinline__ float fast_sigmoid(float x) {
    return 1.0f / (1.0f + __expf(-x));
}
__device__ __forceinline__ float fast_tanh(float x) {
    float ax = fabsf(x);
    float t = 1.0f - 2.0f / (__expf(2.0f * ax) + 1.0f);  // exp(inf)->inf -> t=1
    return copysignf(t, x);
}

// ---------------- weight convert: separate launch, float4-vectorized ----------------
// LESSON (R7): do NOT fuse this into a big-LDS kernel — the fused variant inherited
// normconv's 72KB LDS allocation for 14336 streaming blocks -> 2 blocks/CU -> +35us.
__global__ void k_convert4(const float* __restrict__ s0, const float* __restrict__ s1,
                           const float* __restrict__ s2, const float* __restrict__ s3,
                           const float* __restrict__ s4,
                           unsigned short* __restrict__ d0, unsigned short* __restrict__ d1,
                           unsigned short* __restrict__ d2, unsigned short* __restrict__ d3,
                           unsigned short* __restrict__ d4) {
    int i = (blockIdx.x * blockDim.x + threadIdx.x) * 4;  // total 3670016 elems
    const float* sp; unsigned short* dp; int off;
    if (i < 1048576)      { sp = s0; dp = d0; off = 0; }
    else if (i < 2097152) { sp = s1; dp = d1; off = 1048576; }
    else if (i < 3145728) { sp = s2; dp = d2; off = 2097152; }
    else if (i < 3407872) { sp = s3; dp = d3; off = 3145728; }
    else if (i < 3670016) { sp = s4; dp = d4; off = 3407872; }
    else return;
    int j = i - off;
    float4 v = *(const float4*)(sp + j);
    uint2 o;
    o.x = (unsigned)f2bf(v.x) | ((unsigned)f2bf(v.y) << 16);
    o.y = (unsigned)f2bf(v.z) | ((unsigned)f2bf(v.w) << 16);
    *(uint2*)(dp + j) = o;
}

// ---------------- fused RMSNorm + depthwise conv (strip of 32 rows + 2-row halo) ----------------
// GEOMETRY IS CLOSED — measured both ways (R5 vs R8):
//   32-row strips, 72KB LDS, (256,2): total 349.5 us  <-- keep
//   16-row strips, 40KB LDS, (256,3): total 357.0 us (halo overhead 2x; occupancy gain
//     didn't pay — kernel BW-saturated, not latency-limited). DO NOT SHRINK STRIPS.
__global__ __launch_bounds__(256, 2) void k_normconv(
        const float* __restrict__ x, const float* __restrict__ w,
        const float* __restrict__ dww, const float* __restrict__ dwb,
        unsigned short* __restrict__ xnb, unsigned short* __restrict__ xc) {
    __shared__ unsigned short sxn[36 * 1024];   // 72 KiB: rows l0-2 .. l0+33
    int blk = blockIdx.x;
    int b = blk >> 6, s = blk & 63;
    int l0 = s * 32;
    int t = threadIdx.x;
    int lane = t & 63, wid = t >> 6;

    float4 nw[4];
#pragma unroll
    for (int j = 0; j < 4; ++j) nw[j] = ((const float4*)w)[j * 64 + lane];

    for (int rr = wid; rr < 36; rr += 4) {
        int l = l0 - 2 + rr;
        bool inr = (l >= 0 && l < LL);
        float4 v[4];
#pragma unroll
        for (int j = 0; j < 4; ++j) { v[j].x = 0.f; v[j].y = 0.f; v[j].z = 0.f; v[j].w = 0.f; }
        if (inr) {
            const float4* xp = (const float4*)(x + ((size_t)b * LL + l) * DIMC);
#pragma unroll
            for (int j = 0; j < 4; ++j) v[j] = xp[j * 64 + lane];
        }
        float ss = 0.f;
#pragma unroll
        for (int j = 0; j < 4; ++j)
            ss += v[j].x * v[j].x + v[j].y * v[j].y + v[j].z * v[j].z + v[j].w * v[j].w;
#pragma unroll
        for (int off = 1; off < 64; off <<= 1) ss += __shfl_xor(ss, off, 64);
        float rinv = 1.0f / sqrtf(ss * (1.0f / DIMC) + EPSV);
#pragma unroll
        for (int j = 0; j < 4; ++j) {
            uint2 o;
            o.x = (unsigned)f2bf(nw[j].x * v[j].x * rinv) | ((unsigned)f2bf(nw[j].y * v[j].y * rinv) << 16);
            o.y = (unsigned)f2bf(nw[j].z * v[j].z * rinv) | ((unsigned)f2bf(nw[j].w * v[j].w * rinv) << 16);
            ((uint2*)(sxn + rr * 1024))[j * 64 + lane] = o;
            if (inr && rr >= 2 && rr < 34)
                ((uint2*)(xnb + ((size_t)b * LL + l) * DIMC))[j * 64 + lane] = o;
        }
    }
    __syncthreads();

    float wgt[4][5];
    int c0 = t * 4;
#pragma unroll
    for (int j = 0; j < 4; ++j)
#pragma unroll
        for (int k = 0; k < 5; ++k) wgt[j][k] = dww[(c0 + j) * 5 + k];
    float4 bv = ((const float4*)dwb)[t];
    for (int r = 0; r < 32; ++r) {
        float acc[4] = {bv.x, bv.y, bv.z, bv.w};
#pragma unroll
        for (int k = 0; k < 5; ++k) {
            uint2 rv = ((const uint2*)(sxn + (r + k) * 1024))[t];
            acc[0] += bf2f((unsigned short)(rv.x & 0xffff)) * wgt[0][k];
            acc[1] += bf2f((unsigned short)(rv.x >> 16))    * wgt[1][k];
            acc[2] += bf2f((unsigned short)(rv.y & 0xffff)) * wgt[2][k];
            acc[3] += bf2f((unsigned short)(rv.y >> 16))    * wgt[3][k];
        }
        uint2 o;
        o.x = (unsigned)f2bf(acc[0]) | ((unsigned)f2bf(acc[1]) << 16);
        o.y = (unsigned)f2bf(acc[2]) | ((unsigned)f2bf(acc[3]) << 16);
        ((uint2*)(xc + ((size_t)b * LL + l0 + r) * DIMC))[t] = o;
    }
}

// ---------------- chunked parallel scan (carry folded into pass c) ----------------
// R10: NCHUNK 32->128. scan_a/c were latency-bound: 64 sequentially-DEPENDENT strided
// loads x ~500cyc at 1 block/CU (no TLP). LC=16 cuts the chain 4x and quadruples the
// grid (1024 blocks = 4/CU). Cost: scan_c carry recompute <=127 L2-resident coalesced
// loads + 127-fma chain (~1us). Same recurrence, different partition.
__global__ __launch_bounds__(256) void k_scan_a(const unsigned short* __restrict__ xnb,
                                                const float* __restrict__ alpha,
                                                const float* __restrict__ beta,
                                                float* __restrict__ F) {
    int blk = blockIdx.x;        // b*NCHUNK + k
    int b = blk >> 7, k = blk & (NCHUNK - 1);
    int c = threadIdx.x;
    float a = alpha[c], bt = beta[c];
    const unsigned short* p = xnb + ((size_t)(b * LL + k * LC)) * DIMC + c;
    float h = 0.0f;
    for (int l = 0; l < LC; ++l) h = a * h + bt * bf2f(p[(size_t)l * DIMC]);
    F[(size_t)blk * ACTC + c] = h;
}
__global__ __launch_bounds__(256) void k_scan_c(const unsigned short* __restrict__ xnb,
                                                const float* __restrict__ alpha,
                                                const float* __restrict__ beta,
                                                const float* __restrict__ F,
                                                unsigned short* __restrict__ hs) {
    int blk = blockIdx.x;
    int b = blk >> 7, k = blk & (NCHUNK - 1);
    int c = threadIdx.x;
    float a = alpha[c], bt = beta[c];
    float aL = a;
#pragma unroll
    for (int i = 0; i < 4; ++i) aL *= aL;   // a^16 (= a^LC)
    float T = 0.0f;
    for (int j = 0; j < k; ++j)             // recompute chunk carry (<=127 fma)
        T = F[((size_t)b * NCHUNK + j) * ACTC + c] + aL * T;
    const unsigned short* p = xnb + ((size_t)(b * LL + k * LC)) * DIMC + c;
    unsigned short*       q = hs  + ((size_t)(b * LL + k * LC)) * ACTC + c;
    float h = T;
    for (int l = 0; l < LC; ++l) {
        h = a * h + bt * bf2f(p[(size_t)l * DIMC]);
        q[(size_t)l * ACTC] = f2bf(h);
    }
}

// ---------------- 128x128 MFMA GEMM body (legacy proven structure) ----------------
// MODE 0: +bias, +concat residual (hs | xnb), bf16 out
// MODE 1: dual-B GLU (sigmoid*tanh) + y1 residual, bf16 out
// MODE 3: +bias, +bf16 add, +f32 add, f32 out
// Instantiated via DISTINCTLY NAMED wrapper kernels so rocprof attributes per-mode time.
#define TM 128
#define TN 128
#define BK 64

#define GLOAD_LDS(gp, lp) \
    __builtin_amdgcn_global_load_lds((const __attribute__((address_space(1))) unsigned int*)(gp), \
                                     (__attribute__((address_space(3))) unsigned int*)(lp), 16, 0, 0)

template<int MODE>
__device__ __forceinline__ void gemm_body(
        const unsigned short* __restrict__ A,
        const unsigned short* __restrict__ B0,
        const unsigned short* __restrict__ B1,
        const float* __restrict__ bias0,
        const float* __restrict__ bias1,
        const unsigned short* __restrict__ add0,
        const unsigned short* __restrict__ add1,
        const float* __restrict__ addf,
        float* __restrict__ outf,
        unsigned short* __restrict__ outb,
        int M, int N, int K)
{
    constexpr int LDSB = (MODE == 1) ? 49152 : 32768;
    __shared__ __align__(16) char lds[LDSB];
    unsigned short* sA  = (unsigned short*)lds;
    unsigned short* sB0 = (unsigned short*)(lds + 16384);
    unsigned short* sB1 = (unsigned short*)(lds + 32768);

    int nx = gridDim.x;
    int bid = blockIdx.y * nx + blockIdx.x;
    int xcd = bid & 7, s = bid >> 3;
    int colt = s % nx, rowgrp = s / nx;
    int m0 = (rowgrp * 8 + xcd) * TM;
    int n0 = colt * TN;

    int t = threadIdx.x;
    int w = t >> 6, lane = t & 63;
    int wm = (w >> 1) * 64, wn = (w & 1) * 64;
    int quad = lane >> 4, lm = lane & 15;
    int lm7 = lm & 7;

    f32x4 zero = {0.f, 0.f, 0.f, 0.f};
    f32x4 acc0[4][4];
    f32x4 acc1[(MODE == 1) ? 4 : 1][(MODE == 1) ? 4 : 1];
#pragma unroll
    for (int i = 0; i < 4; ++i)
#pragma unroll
        for (int j = 0; j < 4; ++j) acc0[i][j] = zero;
    if constexpr (MODE == 1) {
#pragma unroll
        for (int i = 0; i < 4; ++i)
#pragma unroll
            for (int j = 0; j < 4; ++j) acc1[i][j] = zero;
    }

    for (int k0 = 0; k0 < K; k0 += BK) {
        __syncthreads();
#pragma unroll
        for (int c = 0; c < 4; ++c) {
            int i = t + c * 256;
            int r = i >> 3;
            int sc = ((i & 7) ^ (r & 7)) << 3;   // swizzled source k-group
            GLOAD_LDS(A  + (size_t)(m0 + r) * K + k0 + sc, sA  + i * 8);
            GLOAD_LDS(B0 + (size_t)(n0 + r) * K + k0 + sc, sB0 + i * 8);
            if constexpr (MODE == 1)
                GLOAD_LDS(B1 + (size_t)(n0 + r) * K + k0 + sc, sB1 + i * 8);
        }
        __syncthreads();

#pragma unroll
        for (int ks = 0; ks < BK; ks += 32) {
            int cgb = ks >> 3;   // 0 or 4
            bf16x8 af[4], b0f[4];
#pragma unroll
            for (int i = 0; i < 4; ++i) {
                int sg = ((cgb + quad) ^ lm7) << 3;
                af[i]  = *(const bf16x8*)(sA  + (wm + i * 16 + lm) * BK + sg);
                b0f[i] = *(const bf16x8*)(sB0 + (wn + i * 16 + lm) * BK + sg);
            }
            if constexpr (MODE == 1) {
                bf16x8 b1f[4];
#pragma unroll
                for (int i = 0; i < 4; ++i)
                    b1f[i] = *(const bf16x8*)(sB1 + (wn + i * 16 + lm) * BK + (((cgb + quad) ^ lm7) << 3));
#pragma unroll
                for (int mi = 0; mi < 4; ++mi)
#pragma unroll
                    for (int ni = 0; ni < 4; ++ni) {
                        acc0[mi][ni] = __builtin_amdgcn_mfma_f32_16x16x32_bf16(af[mi], b0f[ni], acc0[mi][ni], 0, 0, 0);
                        acc1[mi][ni] = __builtin_amdgcn_mfma_f32_16x16x32_bf16(af[mi], b1f[ni], acc1[mi][ni], 0, 0, 0);
                    }
            } else {
#pragma unroll
                for (int mi = 0; mi < 4; ++mi)
#pragma unroll
                    for (int ni = 0; ni < 4; ++ni)
                        acc0[mi][ni] = __builtin_amdgcn_mfma_f32_16x16x32_bf16(af[mi], b0f[ni], acc0[mi][ni], 0, 0, 0);
            }
        }
    }

    __syncthreads();
    if constexpr (MODE == 3) {
        float* sO = (float*)lds;
#pragma unroll
        for (int half = 0; half < 2; ++half) {
            if (wm == half * 64) {
#pragma unroll
                for (int mi = 0; mi < 4; ++mi) {
#pragma unroll
                    for (int ni = 0; ni < 4; ++ni) {
                        int nl = wn + ni * 16 + lm;
                        float bn = bias0[n0 + nl];
#pragma unroll
                        for (int j = 0; j < 4; ++j) {
                            int mloc = mi * 16 + quad * 4 + j;   // 0..63
                            sO[mloc * TN + nl] = acc0[mi][ni][j] + bn;
                        }
                    }
                }
            }
            __syncthreads();
#pragma unroll
            for (int c = 0; c < 8; ++c) {
                int i = t + c * 256;
                int r = i >> 5, c4 = (i & 31) << 2;
                int m = m0 + half * 64 + r, n = n0 + c4;
                float4 v  = *(float4*)(sO + r * TN + c4);
                uint2  ab = *(const uint2*)(add0 + (size_t)m * N + n);
                float4 xf = *(const float4*)(addf + (size_t)m * N + n);
                float4 o;
                o.x = v.x + bf2f((unsigned short)(ab.x & 0xffff)) + xf.x;
                o.y = v.y + bf2f((unsigned short)(ab.x >> 16))    + xf.y;
                o.z = v.z + bf2f((unsigned short)(ab.y & 0xffff)) + xf.z;
                o.w = v.w + bf2f((unsigned short)(ab.y >> 16))    + xf.w;
                *(float4*)(outf + (size_t)m * N + n) = o;
            }
            __syncthreads();
        }
    } else {
        unsigned short* sO = (unsigned short*)lds;
#pragma unroll
        for (int mi = 0; mi < 4; ++mi) {
#pragma unroll
            for (int ni = 0; ni < 4; ++ni) {
                int nl = wn + ni * 16 + lm;
                int n  = n0 + nl;
                float bn = bias0[n];
                float bn1 = (MODE == 1) ? bias1[n] : 0.0f;
#pragma unroll
                for (int j = 0; j < 4; ++j) {
                    int ml = wm + mi * 16 + quad * 4 + j;
                    float v = acc0[mi][ni][j];
                    float r;
                    if constexpr (MODE == 0) {
                        r = v + bn;                       // residual added at store
                    } else {
                        float u1 = v + bn;
                        float u2 = acc1[mi][ni][j] + bn1;
                        r = fast_sigmoid(u1) * fast_tanh(u2);   // y1 added at store
                    }
                    sO[ml * TN + nl] = f2bf(r);
                }
            }
        }
        __syncthreads();
#pragma unroll
        for (int c = 0; c < 8; ++c) {
            int i = t + c * 256;
            int r = i >> 4, c8 = (i & 15) << 3;
            int m = m0 + r, n = n0 + c8;
            uint4 g = *(uint4*)(sO + r * TN + c8);
            uint4 av;
            if constexpr (MODE == 0) {
                av = (n0 < ACTC) ? *(const uint4*)(add0 + (size_t)m * ACTC + n)
                                 : *(const uint4*)(add1 + (size_t)m * DIMC + n);
            } else {
                av = *(const uint4*)(add0 + (size_t)m * N + n);
            }
            unsigned* gp = (unsigned*)&g;
            unsigned* ap = (unsigned*)&av;
            uint4 o;
            unsigned* op = (unsigned*)&o;
#pragma unroll
            for (int q = 0; q < 4; ++q) {
                float lo = bf2f((unsigned short)(gp[q] & 0xffff)) + bf2f((unsigned short)(ap[q] & 0xffff));
                float hi = bf2f((unsigned short)(gp[q] >> 16))    + bf2f((unsigned short)(ap[q] >> 16));
                op[q] = (unsigned)f2bf(lo) | ((unsigned)f2bf(hi) << 16);
            }
            *(uint4*)(outb + (size_t)m * N + n) = o;
        }
    }
}

// Named wrappers (distinct rocprof rows)
__global__ __launch_bounds__(256, 4) void k_gemm_pw(
        const unsigned short* A, const unsigned short* B0, const float* bias0,
        const unsigned short* add0, const unsigned short* add1, unsigned short* outb,
        int M, int N, int K) {
    gemm_body<0>(A, B0, nullptr, bias0, nullptr, add0, add1, nullptr, nullptr, outb, M, N, K);
}
// OCCUPANCY LEVER IS CLOSED — measured both ways:
//   (256,2): VGPR=108, no spill, ~83 us  <-- keep
//   (256,3): allocator caps VGPR at 84, dual 4x4 f32x4 accs spill to scratch
//            (R6: WRITE_SIZE 32->67.5MB, FETCH 58->100MB, 183 us rocprof). DO NOT RAISE.
__global__ __launch_bounds__(256, 2) void k_gemm_glu(
        const unsigned short* A, const unsigned short* B0, const unsigned short* B1,
        const float* bias0, const float* bias1, const unsigned short* add0,
        unsigned short* outb, int M, int N, int K) {
    gemm_body<1>(A, B0, B1, bias0, bias1, add0, nullptr, nullptr, nullptr, outb, M, N, K);
}
__global__ __launch_bounds__(256, 4) void k_gemm_up(
        const unsigned short* A, const unsigned short* B0, const float* bias0,
        const unsigned short* add0, const float* addf, float* outf,
        int M, int N, int K) {
    gemm_body<3>(A, B0, nullptr, bias0, nullptr, add0, nullptr, addf, outf, nullptr, M, N, K);
}

// ---------------- 128x64-tile GEMM: down-proj + gelu ----------------
__global__ __launch_bounds__(256, 4) void k_gemm_dn(
        const unsigned short* __restrict__ A,
        const unsigned short* __restrict__ B0,
        const float* __restrict__ bias0,
        unsigned short* __restrict__ outb,
        int M, int N, int K)
{
    __shared__ __align__(16) char lds[24576];
    unsigned short* sA  = (unsigned short*)lds;                  // 128x64 = 16KB
    unsigned short* sB0 = (unsigned short*)(lds + 16384);        // 64x64  =  8KB

    int nx = gridDim.x;
    int bid = blockIdx.y * nx + blockIdx.x;
    int xcd = bid & 7, s = bid >> 3;
    int colt = s % nx, rowgrp = s / nx;
    int m0 = (rowgrp * 8 + xcd) * TM;
    int n0 = colt * 64;

    int t = threadIdx.x;
    int w = t >> 6, lane = t & 63;
    int wm = (w >> 1) * 64, wn = (w & 1) * 32;   // 2x2 wave grid: 64 rows x 32 cols each
    int quad = lane >> 4, lm = lane & 15;
    int lm7 = lm & 7;

    f32x4 zero = {0.f, 0.f, 0.f, 0.f};
    f32x4 acc0[4][2];
#pragma unroll
    for (int i = 0; i < 4; ++i)
#pragma unroll
        for (int j = 0; j < 2; ++j) acc0[i][j] = zero;

    for (int k0 = 0; k0 < K; k0 += BK) {
        __syncthreads();
#pragma unroll
        for (int c = 0; c < 4; ++c) {            // A: 128 rows, 4 rounds
            int i = t + c * 256;
            int r = i >> 3;
            int sc = ((i & 7) ^ (r & 7)) << 3;
            GLOAD_LDS(A + (size_t)(m0 + r) * K + k0 + sc, sA + i * 8);
        }
#pragma unroll
        for (int c = 0; c < 2; ++c) {            // B: 64 rows, 2 rounds
            int i = t + c * 256;
            int r = i >> 3;
            int sc = ((i & 7) ^ (r & 7)) << 3;
            GLOAD_LDS(B0 + (size_t)(n0 + r) * K + k0 + sc, sB0 + i * 8);
        }
        __syncthreads();

#pragma unroll
        for (int ks = 0; ks < BK; ks += 32) {
            int cgb = ks >> 3;   // 0 or 4
            int sg = ((cgb + quad) ^ lm7) << 3;
            bf16x8 af[4], b0f[2];
#pragma unroll
            for (int i = 0; i < 4; ++i)
                af[i] = *(const bf16x8*)(sA + (wm + i * 16 + lm) * BK + sg);
#pragma unroll
            for (int i = 0; i < 2; ++i)
                b0f[i] = *(const bf16x8*)(sB0 + (wn + i * 16 + lm) * BK + sg);
#pragma unroll
            for (int mi = 0; mi < 4; ++mi)
#pragma unroll
                for (int ni = 0; ni < 2; ++ni)
                    acc0[mi][ni] = __builtin_amdgcn_mfma_f32_16x16x32_bf16(af[mi], b0f[ni], acc0[mi][ni], 0, 0, 0);
        }
    }

    // epilogue: acc -> bf16 LDS pack [128][64] -> coalesced store
    __syncthreads();
    unsigned short* sO = (unsigned short*)lds;
#pragma unroll
    for (int mi = 0; mi < 4; ++mi) {
#pragma unroll
        for (int ni = 0; ni < 2; ++ni) {
            int nl = wn + ni * 16 + lm;
            int n  = n0 + nl;
            float bn = bias0[n];
#pragma unroll
            for (int j = 0; j < 4; ++j) {
                int ml = wm + mi * 16 + quad * 4 + j;
                float u = acc0[mi][ni][j] + bn;
                float r = 0.5f * u * (1.0f + erff(u * 0.70710678118654752f));
                sO[ml * 64 + nl] = f2bf(r);
            }
        }
    }
    __syncthreads();
#pragma unroll
    for (int c = 0; c < 4; ++c) {
        int i = t + c * 256;
        int r = i >> 3, c8 = (i & 7) << 3;
        int m = m0 + r, n = n0 + c8;
        uint4 g = *(uint4*)(sO + r * 64 + c8);
        *(uint4*)(outb + (size_t)m * N + n) = g;
    }
}

extern "C" void kernel_launch(void* const* d_in, const int* in_sizes, int n_in,
                              void* d_out, int out_size, void* d_ws, size_t ws_size,
                              hipStream_t stream) {
    (void)in_sizes; (void)n_in; (void)out_size; (void)ws_size;
    const float* x      = (const float*)d_in[0];
    const float* norm_w = (const float*)d_in[1];
    const float* dw_w   = (const float*)d_in[2];
    const float* dw_b   = (const float*)d_in[3];
    const float* pw_w   = (const float*)d_in[4];
    const float* pw_b   = (const float*)d_in[5];
    const float* alpha  = (const float*)d_in[6];
    const float* beta   = (const float*)d_in[7];
    const float* W1_w   = (const float*)d_in[8];
    const float* W1_b   = (const float*)d_in[9];
    const float* W2_w   = (const float*)d_in[10];
    const float* W2_b   = (const float*)d_in[11];
    const float* down_w = (const float*)d_in[12];
    const float* down_b = (const float*)d_in[13];
    const float* up_w   = (const float*)d_in[14];
    const float* up_b   = (const float*)d_in[15];

    char* ws = (char*)d_ws;
    unsigned short* xnb  = (unsigned short*)(ws);
    unsigned short* xc   = (unsigned short*)(ws + 33554432ull);
    unsigned short* hs   = (unsigned short*)(ws + 67108864ull);
    unsigned short* y1b  = (unsigned short*)(ws + 75497472ull);
    unsigned short* y2b  = (unsigned short*)(ws + 109051904ull);
    unsigned short* gact = (unsigned short*)(ws + 142606336ull);
    unsigned short* wpw  = (unsigned short*)(ws + 150994944ull);
    unsigned short* w1b  = wpw + 1048576;
    unsigned short* w2b  = w1b + 1048576;
    unsigned short* wdn  = w2b + 1048576;
    unsigned short* wup  = wdn + 262144;
    // F = BB*NCHUNK*ACTC f32 = 1 MB. Placed in the verified-free gap between the
    // weight region end (ws+158334976) and the legacy Fb offset (ws+159383552),
    // so total workspace footprint does not grow past previously-used bounds.
    float*          Fb   = (float*)(ws + 158334976ull);

    k_convert4<<<3584, 256, 0, stream>>>(pw_w, W1_w, W2_w, down_w, up_w,
                                         wpw, w1b, w2b, wdn, wup);

    k_normconv<<<BB * 64, 256, 0, stream>>>(x, norm_w, dw_w, dw_b, xnb, xc);

    k_scan_a<<<BB * NCHUNK, ACTC, 0, stream>>>(xnb, alpha, beta, Fb);
    k_scan_c<<<BB * NCHUNK, ACTC, 0, stream>>>(xnb, alpha, beta, Fb, hs);

    dim3 g0(DIMC / TN, MROWS / TM);          // (8, 128)  = 1024 blocks
    dim3 g2(HIDC / 64, MROWS / TM);          // (4, 128)  = 512 blocks
    k_gemm_pw <<<g0, 256, 0, stream>>>(xc, wpw, pw_b, hs, xnb, y1b, MROWS, DIMC, DIMC);
    k_gemm_glu<<<g0, 256, 0, stream>>>(y1b, w1b, w2b, W1_b, W2_b, y1b, y2b, MROWS, DIMC, DIMC);
    k_gemm_dn <<<g2, 256, 0, stream>>>(y2b, wdn, down_b, gact, MROWS, HIDC, DIMC);
    k_gemm_up <<<g0, 256, 0, stream>>>(gact, wup, up_b, y2b, x, (float*)d_out, MROWS, DIMC, HIDC);
}

// Round 11
// 341.012 us; speedup vs baseline: 1.0944x; 1.0944x over previous
//
#include <hip/hip_runtime.h>
#include <math.h>

#define DIMC 1024
#define BB   8
#define LL   2048
#define ACTC 256
#define HIDC 256
#define EPSV 1e-6f
#define MROWS (BB * LL)   // 16384
#define NCHUNK 32         // SCAN GEOMETRY CLOSED: 32 (R9, 359.7) beats 128 (R10, 373.2).
#define LC     64         // LL / NCHUNK

typedef __bf16 bf16x8 __attribute__((ext_vector_type(8)));
typedef float  f32x4  __attribute__((ext_vector_type(4)));

__device__ __forceinline__ unsigned short f2bf(float f) {
    union { float f; unsigned int u; } v; v.f = f;
    unsigned int u = v.u + 0x7fffu + ((v.u >> 16) & 1u);
    return (unsigned short)(u >> 16);
}
__device__ __forceinline__ float bf2f(unsigned short s) {
    union { float f; unsigned int u; } v; v.u = ((unsigned int)s) << 16;
    return v.f;
}
// inf-safe fast sigmoid/tanh on native v_exp_f32
__device__ __forceinline__ float fast_sigmoid(float x) {
    return 1.0f / (1.0f + __expf(-x));
}
__device__ __forceinline__ float fast_tanh(float x) {
    float ax = fabsf(x);
    float t = 1.0f - 2.0f / (__expf(2.0f * ax) + 1.0f);  // exp(inf)->inf -> t=1
    return copysignf(t, x);
}

// ---------------- weight convert: separate launch, float4-vectorized ----------------
// LESSON (R7): do NOT fuse this into a big-LDS kernel — the fused variant inherited
// normconv's 72KB LDS allocation for 14336 streaming blocks -> 2 blocks/CU -> +35us.
__global__ void k_convert4(const float* __restrict__ s0, const float* __restrict__ s1,
                           const float* __restrict__ s2, const float* __restrict__ s3,
                           const float* __restrict__ s4,
                           unsigned short* __restrict__ d0, unsigned short* __restrict__ d1,
                           unsigned short* __restrict__ d2, unsigned short* __restrict__ d3,
                           unsigned short* __restrict__ d4) {
    int i = (blockIdx.x * blockDim.x + threadIdx.x) * 4;  // total 3670016 elems
    const float* sp; unsigned short* dp; int off;
    if (i < 1048576)      { sp = s0; dp = d0; off = 0; }
    else if (i < 2097152) { sp = s1; dp = d1; off = 1048576; }
    else if (i < 3145728) { sp = s2; dp = d2; off = 2097152; }
    else if (i < 3407872) { sp = s3; dp = d3; off = 3145728; }
    else if (i < 3670016) { sp = s4; dp = d4; off = 3407872; }
    else return;
    int j = i - off;
    float4 v = *(const float4*)(sp + j);
    uint2 o;
    o.x = (unsigned)f2bf(v.x) | ((unsigned)f2bf(v.y) << 16);
    o.y = (unsigned)f2bf(v.z) | ((unsigned)f2bf(v.w) << 16);
    *(uint2*)(dp + j) = o;
}

// ---------------- fused RMSNorm + depthwise conv (strip of 32 rows + 2-row halo) ----------------
// GEOMETRY IS CLOSED — measured both ways (R5 vs R8):
//   32-row strips, 72KB LDS, (256,2): total 349.5 us  <-- keep
//   16-row strips, 40KB LDS, (256,3): total 357.0 us (halo overhead 2x; occupancy gain
//     didn't pay — kernel BW-saturated, not latency-limited). DO NOT SHRINK STRIPS.
__global__ __launch_bounds__(256, 2) void k_normconv(
        const float* __restrict__ x, const float* __restrict__ w,
        const float* __restrict__ dww, const float* __restrict__ dwb,
        unsigned short* __restrict__ xnb, unsigned short* __restrict__ xc) {
    __shared__ unsigned short sxn[36 * 1024];   // 72 KiB: rows l0-2 .. l0+33
    int blk = blockIdx.x;
    int b = blk >> 6, s = blk & 63;
    int l0 = s * 32;
    int t = threadIdx.x;
    int lane = t & 63, wid = t >> 6;

    float4 nw[4];
#pragma unroll
    for (int j = 0; j < 4; ++j) nw[j] = ((const float4*)w)[j * 64 + lane];

    for (int rr = wid; rr < 36; rr += 4) {
        int l = l0 - 2 + rr;
        bool inr = (l >= 0 && l < LL);
        float4 v[4];
#pragma unroll
        for (int j = 0; j < 4; ++j) { v[j].x = 0.f; v[j].y = 0.f; v[j].z = 0.f; v[j].w = 0.f; }
        if (inr) {
            const float4* xp = (const float4*)(x + ((size_t)b * LL + l) * DIMC);
#pragma unroll
            for (int j = 0; j < 4; ++j) v[j] = xp[j * 64 + lane];
        }
        float ss = 0.f;
#pragma unroll
        for (int j = 0; j < 4; ++j)
            ss += v[j].x * v[j].x + v[j].y * v[j].y + v[j].z * v[j].z + v[j].w * v[j].w;
#pragma unroll
        for (int off = 1; off < 64; off <<= 1) ss += __shfl_xor(ss, off, 64);
        float rinv = 1.0f / sqrtf(ss * (1.0f / DIMC) + EPSV);
#pragma unroll
        for (int j = 0; j < 4; ++j) {
            uint2 o;
            o.x = (unsigned)f2bf(nw[j].x * v[j].x * rinv) | ((unsigned)f2bf(nw[j].y * v[j].y * rinv) << 16);
            o.y = (unsigned)f2bf(nw[j].z * v[j].z * rinv) | ((unsigned)f2bf(nw[j].w * v[j].w * rinv) << 16);
            ((uint2*)(sxn + rr * 1024))[j * 64 + lane] = o;
            if (inr && rr >= 2 && rr < 34)
                ((uint2*)(xnb + ((size_t)b * LL + l) * DIMC))[j * 64 + lane] = o;
        }
    }
    __syncthreads();

    float wgt[4][5];
    int c0 = t * 4;
#pragma unroll
    for (int j = 0; j < 4; ++j)
#pragma unroll
        for (int k = 0; k < 5; ++k) wgt[j][k] = dww[(c0 + j) * 5 + k];
    float4 bv = ((const float4*)dwb)[t];
    for (int r = 0; r < 32; ++r) {
        float acc[4] = {bv.x, bv.y, bv.z, bv.w};
#pragma unroll
        for (int k = 0; k < 5; ++k) {
            uint2 rv = ((const uint2*)(sxn + (r + k) * 1024))[t];
            acc[0] += bf2f((unsigned short)(rv.x & 0xffff)) * wgt[0][k];
            acc[1] += bf2f((unsigned short)(rv.x >> 16))    * wgt[1][k];
            acc[2] += bf2f((unsigned short)(rv.y & 0xffff)) * wgt[2][k];
            acc[3] += bf2f((unsigned short)(rv.y >> 16))    * wgt[3][k];
        }
        uint2 o;
        o.x = (unsigned)f2bf(acc[0]) | ((unsigned)f2bf(acc[1]) << 16);
        o.y = (unsigned)f2bf(acc[2]) | ((unsigned)f2bf(acc[3]) << 16);
        ((uint2*)(xc + ((size_t)b * LL + l0 + r) * DIMC))[t] = o;
    }
}

// ---------------- chunked parallel scan (carry folded into pass c) ----------------
// SCAN GEOMETRY CLOSED — measured both ways:
//   NCHUNK=32  (LC=64): total 359.7 us (R9)  <-- keep
//   NCHUNK=128 (LC=16): total 373.2 us (R10; O(NCHUNK^2) carry-recompute F-traffic +
//     tiny per-block work swamped the latency gain). DO NOT RE-CHUNK.
__global__ __launch_bounds__(256) void k_scan_a(const unsigned short* __restrict__ xnb,
                                                const float* __restrict__ alpha,
                                                const float* __restrict__ beta,
                                                float* __restrict__ F) {
    int blk = blockIdx.x;        // b*NCHUNK + k
    int b = blk >> 5, k = blk & (NCHUNK - 1);
    int c = threadIdx.x;
    float a = alpha[c], bt = beta[c];
    const unsigned short* p = xnb + ((size_t)(b * LL + k * LC)) * DIMC + c;
    float h = 0.0f;
    for (int l = 0; l < LC; ++l) h = a * h + bt * bf2f(p[(size_t)l * DIMC]);
    F[(size_t)blk * ACTC + c] = h;
}
__global__ __launch_bounds__(256) void k_scan_c(const unsigned short* __restrict__ xnb,
                                                const float* __restrict__ alpha,
                                                const float* __restrict__ beta,
                                                const float* __restrict__ F,
                                                unsigned short* __restrict__ hs) {
    int blk = blockIdx.x;
    int b = blk >> 5, k = blk & (NCHUNK - 1);
    int c = threadIdx.x;
    float a = alpha[c], bt = beta[c];
    float aL = a;
#pragma unroll
    for (int i = 0; i < 6; ++i) aL *= aL;   // a^64 (= a^LC)
    float T = 0.0f;
    for (int j = 0; j < k; ++j)             // recompute chunk carry (<=31 fma, replaces scan_b)
        T = F[((size_t)b * NCHUNK + j) * ACTC + c] + aL * T;
    const unsigned short* p = xnb + ((size_t)(b * LL + k * LC)) * DIMC + c;
    unsigned short*       q = hs  + ((size_t)(b * LL + k * LC)) * ACTC + c;
    float h = T;
    for (int l = 0; l < LC; ++l) {
        h = a * h + bt * bf2f(p[(size_t)l * DIMC]);
        q[(size_t)l * ACTC] = f2bf(h);
    }
}

// ---------------- 128x128 MFMA GEMM body (legacy proven structure) ----------------
// MODE 0: +bias, +concat residual (hs | xnb), bf16 out
// MODE 1: dual-B GLU (sigmoid*tanh) + y1 residual, bf16 out
// MODE 3: +bias, +bf16 add, +f32 add, f32 out
// Instantiated via DISTINCTLY NAMED wrapper kernels so rocprof attributes per-mode time.
#define TM 128
#define TN 128
#define BK 64

#define GLOAD_LDS(gp, lp) \
    __builtin_amdgcn_global_load_lds((const __attribute__((address_space(1))) unsigned int*)(gp), \
                                     (__attribute__((address_space(3))) unsigned int*)(lp), 16, 0, 0)

template<int MODE>
__device__ __forceinline__ void gemm_body(
        const unsigned short* __restrict__ A,
        const unsigned short* __restrict__ B0,
        const unsigned short* __restrict__ B1,
        const float* __restrict__ bias0,
        const float* __restrict__ bias1,
        const unsigned short* __restrict__ add0,
        const unsigned short* __restrict__ add1,
        const float* __restrict__ addf,
        float* __restrict__ outf,
        unsigned short* __restrict__ outb,
        int M, int N, int K)
{
    constexpr int LDSB = (MODE == 1) ? 49152 : 32768;
    __shared__ __align__(16) char lds[LDSB];
    unsigned short* sA  = (unsigned short*)lds;
    unsigned short* sB0 = (unsigned short*)(lds + 16384);
    unsigned short* sB1 = (unsigned short*)(lds + 32768);

    int nx = gridDim.x;
    int bid = blockIdx.y * nx + blockIdx.x;
    int xcd = bid & 7, s = bid >> 3;
    int colt = s % nx, rowgrp = s / nx;
    int m0 = (rowgrp * 8 + xcd) * TM;
    int n0 = colt * TN;

    int t = threadIdx.x;
    int w = t >> 6, lane = t & 63;
    int wm = (w >> 1) * 64, wn = (w & 1) * 64;
    int quad = lane >> 4, lm = lane & 15;
    int lm7 = lm & 7;

    f32x4 zero = {0.f, 0.f, 0.f, 0.f};
    f32x4 acc0[4][4];
    f32x4 acc1[(MODE == 1) ? 4 : 1][(MODE == 1) ? 4 : 1];
#pragma unroll
    for (int i = 0; i < 4; ++i)
#pragma unroll
        for (int j = 0; j < 4; ++j) acc0[i][j] = zero;
    if constexpr (MODE == 1) {
#pragma unroll
        for (int i = 0; i < 4; ++i)
#pragma unroll
            for (int j = 0; j < 4; ++j) acc1[i][j] = zero;
    }

    for (int k0 = 0; k0 < K; k0 += BK) {
        __syncthreads();
#pragma unroll
        for (int c = 0; c < 4; ++c) {
            int i = t + c * 256;
            int r = i >> 3;
            int sc = ((i & 7) ^ (r & 7)) << 3;   // swizzled source k-group
            GLOAD_LDS(A  + (size_t)(m0 + r) * K + k0 + sc, sA  + i * 8);
            GLOAD_LDS(B0 + (size_t)(n0 + r) * K + k0 + sc, sB0 + i * 8);
            if constexpr (MODE == 1)
                GLOAD_LDS(B1 + (size_t)(n0 + r) * K + k0 + sc, sB1 + i * 8);
        }
        __syncthreads();

#pragma unroll
        for (int ks = 0; ks < BK; ks += 32) {
            int cgb = ks >> 3;   // 0 or 4
            bf16x8 af[4], b0f[4];
#pragma unroll
            for (int i = 0; i < 4; ++i) {
                int sg = ((cgb + quad) ^ lm7) << 3;
                af[i]  = *(const bf16x8*)(sA  + (wm + i * 16 + lm) * BK + sg);
                b0f[i] = *(const bf16x8*)(sB0 + (wn + i * 16 + lm) * BK + sg);
            }
            if constexpr (MODE == 1) {
                bf16x8 b1f[4];
#pragma unroll
                for (int i = 0; i < 4; ++i)
                    b1f[i] = *(const bf16x8*)(sB1 + (wn + i * 16 + lm) * BK + (((cgb + quad) ^ lm7) << 3));
#pragma unroll
                for (int mi = 0; mi < 4; ++mi)
#pragma unroll
                    for (int ni = 0; ni < 4; ++ni) {
                        acc0[mi][ni] = __builtin_amdgcn_mfma_f32_16x16x32_bf16(af[mi], b0f[ni], acc0[mi][ni], 0, 0, 0);
                        acc1[mi][ni] = __builtin_amdgcn_mfma_f32_16x16x32_bf16(af[mi], b1f[ni], acc1[mi][ni], 0, 0, 0);
                    }
            } else {
#pragma unroll
                for (int mi = 0; mi < 4; ++mi)
#pragma unroll
                    for (int ni = 0; ni < 4; ++ni)
                        acc0[mi][ni] = __builtin_amdgcn_mfma_f32_16x16x32_bf16(af[mi], b0f[ni], acc0[mi][ni], 0, 0, 0);
            }
        }
    }

    __syncthreads();
    if constexpr (MODE == 3) {
        float* sO = (float*)lds;
#pragma unroll
        for (int half = 0; half < 2; ++half) {
            if (wm == half * 64) {
#pragma unroll
                for (int mi = 0; mi < 4; ++mi) {
#pragma unroll
                    for (int ni = 0; ni < 4; ++ni) {
                        int nl = wn + ni * 16 + lm;
                        float bn = bias0[n0 + nl];
#pragma unroll
                        for (int j = 0; j < 4; ++j) {
                            int mloc = mi * 16 + quad * 4 + j;   // 0..63
                            sO[mloc * TN + nl] = acc0[mi][ni][j] + bn;
                        }
                    }
                }
            }
            __syncthreads();
#pragma unroll
            for (int c = 0; c < 8; ++c) {
                int i = t + c * 256;
                int r = i >> 5, c4 = (i & 31) << 2;
                int m = m0 + half * 64 + r, n = n0 + c4;
                float4 v  = *(float4*)(sO + r * TN + c4);
                uint2  ab = *(const uint2*)(add0 + (size_t)m * N + n);
                float4 xf = *(const float4*)(addf + (size_t)m * N + n);
                float4 o;
                o.x = v.x + bf2f((unsigned short)(ab.x & 0xffff)) + xf.x;
                o.y = v.y + bf2f((unsigned short)(ab.x >> 16))    + xf.y;
                o.z = v.z + bf2f((unsigned short)(ab.y & 0xffff)) + xf.z;
                o.w = v.w + bf2f((unsigned short)(ab.y >> 16))    + xf.w;
                *(float4*)(outf + (size_t)m * N + n) = o;
            }
            __syncthreads();
        }
    } else {
        unsigned short* sO = (unsigned short*)lds;
#pragma unroll
        for (int mi = 0; mi < 4; ++mi) {
#pragma unroll
            for (int ni = 0; ni < 4; ++ni) {
                int nl = wn + ni * 16 + lm;
                int n  = n0 + nl;
                float bn = bias0[n];
                float bn1 = (MODE == 1) ? bias1[n] : 0.0f;
#pragma unroll
                for (int j = 0; j < 4; ++j) {
                    int ml = wm + mi * 16 + quad * 4 + j;
                    float v = acc0[mi][ni][j];
                    float r;
                    if constexpr (MODE == 0) {
                        r = v + bn;                       // residual added at store
                    } else {
                        float u1 = v + bn;
                        float u2 = acc1[mi][ni][j] + bn1;
                        r = fast_sigmoid(u1) * fast_tanh(u2);   // y1 added at store
                    }
                    sO[ml * TN + nl] = f2bf(r);
                }
            }
        }
        __syncthreads();
#pragma unroll
        for (int c = 0; c < 8; ++c) {
            int i = t + c * 256;
            int r = i >> 4, c8 = (i & 15) << 3;
            int m = m0 + r, n = n0 + c8;
            uint4 g = *(uint4*)(sO + r * TN + c8);
            uint4 av;
            if constexpr (MODE == 0) {
                av = (n0 < ACTC) ? *(const uint4*)(add0 + (size_t)m * ACTC + n)
                                 : *(const uint4*)(add1 + (size_t)m * DIMC + n);
            } else {
                av = *(const uint4*)(add0 + (size_t)m * N + n);
            }
            unsigned* gp = (unsigned*)&g;
            unsigned* ap = (unsigned*)&av;
            uint4 o;
            unsigned* op = (unsigned*)&o;
#pragma unroll
            for (int q = 0; q < 4; ++q) {
                float lo = bf2f((unsigned short)(gp[q] & 0xffff)) + bf2f((unsigned short)(ap[q] & 0xffff));
                float hi = bf2f((unsigned short)(gp[q] >> 16))    + bf2f((unsigned short)(ap[q] >> 16));
                op[q] = (unsigned)f2bf(lo) | ((unsigned)f2bf(hi) << 16);
            }
            *(uint4*)(outb + (size_t)m * N + n) = o;
        }
    }
}

// Named wrappers (distinct rocprof rows)
__global__ __launch_bounds__(256, 4) void k_gemm_pw(
        const unsigned short* A, const unsigned short* B0, const float* bias0,
        const unsigned short* add0, const unsigned short* add1, unsigned short* outb,
        int M, int N, int K) {
    gemm_body<0>(A, B0, nullptr, bias0, nullptr, add0, add1, nullptr, nullptr, outb, M, N, K);
}
// OCCUPANCY LEVER IS CLOSED — measured both ways:
//   (256,2): VGPR=108, no spill, ~83 us  <-- keep
//   (256,3): allocator caps VGPR at 84, dual 4x4 f32x4 accs spill to scratch
//            (R6: WRITE_SIZE 32->67.5MB, FETCH 58->100MB, 183 us rocprof). DO NOT RAISE.
__global__ __launch_bounds__(256, 2) void k_gemm_glu(
        const unsigned short* A, const unsigned short* B0, const unsigned short* B1,
        const float* bias0, const float* bias1, const unsigned short* add0,
        unsigned short* outb, int M, int N, int K) {
    gemm_body<1>(A, B0, B1, bias0, bias1, add0, nullptr, nullptr, nullptr, outb, M, N, K);
}
__global__ __launch_bounds__(256, 4) void k_gemm_up(
        const unsigned short* A, const unsigned short* B0, const float* bias0,
        const unsigned short* add0, const float* addf, float* outf,
        int M, int N, int K) {
    gemm_body<3>(A, B0, nullptr, bias0, nullptr, add0, nullptr, addf, outf, nullptr, M, N, K);
}

// ---------------- 128x64-tile GEMM: down-proj + gelu ----------------
__global__ __launch_bounds__(256, 4) void k_gemm_dn(
        const unsigned short* __restrict__ A,
        const unsigned short* __restrict__ B0,
        const float* __restrict__ bias0,
        unsigned short* __restrict__ outb,
        int M, int N, int K)
{
    __shared__ __align__(16) char lds[24576];
    unsigned short* sA  = (unsigned short*)lds;                  // 128x64 = 16KB
    unsigned short* sB0 = (unsigned short*)(lds + 16384);        // 64x64  =  8KB

    int nx = gridDim.x;
    int bid = blockIdx.y * nx + blockIdx.x;
    int xcd = bid & 7, s = bid >> 3;
    int colt = s % nx, rowgrp = s / nx;
    int m0 = (rowgrp * 8 + xcd) * TM;
    int n0 = colt * 64;

    int t = threadIdx.x;
    int w = t >> 6, lane = t & 63;
    int wm = (w >> 1) * 64, wn = (w & 1) * 32;   // 2x2 wave grid: 64 rows x 32 cols each
    int quad = lane >> 4, lm = lane & 15;
    int lm7 = lm & 7;

    f32x4 zero = {0.f, 0.f, 0.f, 0.f};
    f32x4 acc0[4][2];
#pragma unroll
    for (int i = 0; i < 4; ++i)
#pragma unroll
        for (int j = 0; j < 2; ++j) acc0[i][j] = zero;

    for (int k0 = 0; k0 < K; k0 += BK) {
        __syncthreads();
#pragma unroll
        for (int c = 0; c < 4; ++c) {            // A: 128 rows, 4 rounds
            int i = t + c * 256;
            int r = i >> 3;
            int sc = ((i & 7) ^ (r & 7)) << 3;
            GLOAD_LDS(A + (size_t)(m0 + r) * K + k0 + sc, sA + i * 8);
        }
#pragma unroll
        for (int c = 0; c < 2; ++c) {            // B: 64 rows, 2 rounds
            int i = t + c * 256;
            int r = i >> 3;
            int sc = ((i & 7) ^ (r & 7)) << 3;
            GLOAD_LDS(B0 + (size_t)(n0 + r) * K + k0 + sc, sB0 + i * 8);
        }
        __syncthreads();

#pragma unroll
        for (int ks = 0; ks < BK; ks += 32) {
            int cgb = ks >> 3;   // 0 or 4
            int sg = ((cgb + quad) ^ lm7) << 3;
            bf16x8 af[4], b0f[2];
#pragma unroll
            for (int i = 0; i < 4; ++i)
                af[i] = *(const bf16x8*)(sA + (wm + i * 16 + lm) * BK + sg);
#pragma unroll
            for (int i = 0; i < 2; ++i)
                b0f[i] = *(const bf16x8*)(sB0 + (wn + i * 16 + lm) * BK + sg);
#pragma unroll
            for (int mi = 0; mi < 4; ++mi)
#pragma unroll
                for (int ni = 0; ni < 2; ++ni)
                    acc0[mi][ni] = __builtin_amdgcn_mfma_f32_16x16x32_bf16(af[mi], b0f[ni], acc0[mi][ni], 0, 0, 0);
        }
    }

    // epilogue: acc -> bf16 LDS pack [128][64] -> coalesced store
    __syncthreads();
    unsigned short* sO = (unsigned short*)lds;
#pragma unroll
    for (int mi = 0; mi < 4; ++mi) {
#pragma unroll
        for (int ni = 0; ni < 2; ++ni) {
            int nl = wn + ni * 16 + lm;
            int n  = n0 + nl;
            float bn = bias0[n];
#pragma unroll
            for (int j = 0; j < 4; ++j) {
                int ml = wm + mi * 16 + quad * 4 + j;
                float u = acc0[mi][ni][j] + bn;
                float r = 0.5f * u * (1.0f + erff(u * 0.70710678118654752f));
                sO[ml * 64 + nl] = f2bf(r);
            }
        }
    }
    __syncthreads();
#pragma unroll
    for (int c = 0; c < 4; ++c) {
        int i = t + c * 256;
        int r = i >> 3, c8 = (i & 7) << 3;
        int m = m0 + r, n = n0 + c8;
        uint4 g = *(uint4*)(sO + r * 64 + c8);
        *(uint4*)(outb + (size_t)m * N + n) = g;
    }
}

extern "C" void kernel_launch(void* const* d_in, const int* in_sizes, int n_in,
                              void* d_out, int out_size, void* d_ws, size_t ws_size,
                              hipStream_t stream) {
    (void)in_sizes; (void)n_in; (void)out_size; (void)ws_size;
    const float* x      = (const float*)d_in[0];
    const float* norm_w = (const float*)d_in[1];
    const float* dw_w   = (const float*)d_in[2];
    const float* dw_b   = (const float*)d_in[3];
    const float* pw_w   = (const float*)d_in[4];
    const float* pw_b   = (const float*)d_in[5];
    const float* alpha  = (const float*)d_in[6];
    const float* beta   = (const float*)d_in[7];
    const float* W1_w   = (const float*)d_in[8];
    const float* W1_b   = (const float*)d_in[9];
    const float* W2_w   = (const float*)d_in[10];
    const float* W2_b   = (const float*)d_in[11];
    const float* down_w = (const float*)d_in[12];
    const float* down_b = (const float*)d_in[13];
    const float* up_w   = (const float*)d_in[14];
    const float* up_b   = (const float*)d_in[15];

    char* ws = (char*)d_ws;
    unsigned short* xnb  = (unsigned short*)(ws);
    unsigned short* xc   = (unsigned short*)(ws + 33554432ull);
    unsigned short* hs   = (unsigned short*)(ws + 67108864ull);
    unsigned short* y1b  = (unsigned short*)(ws + 75497472ull);
    unsigned short* y2b  = (unsigned short*)(ws + 109051904ull);
    unsigned short* gact = (unsigned short*)(ws + 142606336ull);
    unsigned short* wpw  = (unsigned short*)(ws + 150994944ull);
    unsigned short* w1b  = wpw + 1048576;
    unsigned short* w2b  = w1b + 1048576;
    unsigned short* wdn  = w2b + 1048576;
    unsigned short* wup  = wdn + 262144;
    float*          Fb   = (float*)(ws + 159383552ull);

    k_convert4<<<3584, 256, 0, stream>>>(pw_w, W1_w, W2_w, down_w, up_w,
                                         wpw, w1b, w2b, wdn, wup);

    k_normconv<<<BB * 64, 256, 0, stream>>>(x, norm_w, dw_w, dw_b, xnb, xc);

    k_scan_a<<<BB * NCHUNK, ACTC, 0, stream>>>(xnb, alpha, beta, Fb);
    k_scan_c<<<BB * NCHUNK, ACTC, 0, stream>>>(xnb, alpha, beta, Fb, hs);

    dim3 g0(DIMC / TN, MROWS / TM);          // (8, 128)  = 1024 blocks
    dim3 g2(HIDC / 64, MROWS / TM);          // (4, 128)  = 512 blocks
    k_gemm_pw <<<g0, 256, 0, stream>>>(xc, wpw, pw_b, hs, xnb, y1b, MROWS, DIMC, DIMC);
    k_gemm_glu<<<g0, 256, 0, stream>>>(y1b, w1b, w2b, W1_b, W2_b, y1b, y2b, MROWS, DIMC, DIMC);
    k_gemm_dn <<<g2, 256, 0, stream>>>(y2b, wdn, down_b, gact, MROWS, HIDC, DIMC);
    k_gemm_up <<<g0, 256, 0, stream>>>(gact, wup, up_b, y2b, x, (float*)d_out, MROWS, DIMC, HIDC);
}